// Round 5
// baseline (1061.078 us; speedup 1.0000x reference)
//
#include <hip/hip_runtime.h>
#include <math.h>

constexpr int B  = 4;
constexpr int S  = 12;
constexpr int N  = 20000;
constexpr int HD = 64;
constexpr int E0 = 640000;
constexpr int EL = E0 + N;      // edges + self loops
constexpr int BN = B * N;
constexpr int CAP = 128;        // padded CSR bucket capacity (deg: mean 32, sd 5.7)

// ---------------- padded-bucket CSR build: one kernel, no scan ---------------
__global__ void scatter_kernel(const int* __restrict__ ei, int* __restrict__ cnt,
                               int* __restrict__ perm) {
    int e = blockIdx.x * blockDim.x + threadIdx.x;
    if (e >= EL) return;
    int s, d;
    if (e < E0) { s = ei[e]; d = ei[E0 + e]; }
    else        { s = e - E0; d = s; }
    int pos = atomicAdd(&cnt[d], 1) & (CAP - 1);   // mask: can't corrupt neighbors
    perm[d * CAP + pos] = s;
}

// ---- conv weight transpose: cwD[dt*4096 + c*64 + o] = cw[o*192 + c*3 + dt] --
__global__ void tw_kernel(const float* __restrict__ cw, float* __restrict__ cwD) {
    int i = blockIdx.x * blockDim.x + threadIdx.x;
    if (i >= HD * HD * 3) return;
    int o = i / (HD * 3), rem = i % (HD * 3), c = rem / 3, dt = rem % 3;
    cwD[dt * (HD * HD) + c * HD + o] = cw[i];
}

// ======== gemm family v3 (R13-proven): lane = k, weights resident in VGPRs ==
// wave processes 16 nodes; node rows broadcast from LDS (wave-uniform addr);
// xe stored directly (coalesced 256B per node); es/ed via butterfly shuffle.
// (v4 1-wave s_load variant measured +9us/dispatch worse — R15.)
constexpr int GT = 64;                  // nodes per block (4 waves x 16)

template<int H>
__global__ __launch_bounds__(256, 4)
void gemm_attn_kernel(const float* __restrict__ hin, const float* __restrict__ w,
                      const float* __restrict__ asrc, const float* __restrict__ adst,
                      float* __restrict__ xe, float* __restrict__ es, float* __restrict__ ed) {
    __shared__ float tile[GT * HD];
    int base = blockIdx.x * GT;
    for (int i = threadIdx.x; i < GT * (HD / 4); i += 256)
        ((float4*)tile)[i] = ((const float4*)(hin + (size_t)base * HD))[i];
    int lane = threadIdx.x & 63;
    float wres[HD];                     // w[c][lane], c compile-time -> VGPRs
    #pragma unroll
    for (int c = 0; c < HD; ++c) wres[c] = w[c * HD + lane];
    float as_ = asrc[lane], ad_ = adst[lane];
    __syncthreads();
    int wvid = threadIdx.x >> 6;
    for (int j = wvid * 16; j < wvid * 16 + 16; ++j) {
        int t = base + j;
        float acc = 0.f;
        #pragma unroll
        for (int cq = 0; cq < 16; ++cq) {
            float4 r = ((const float4*)tile)[j * 16 + cq];   // broadcast read
            acc = fmaf(r.x, wres[4 * cq + 0], acc);
            acc = fmaf(r.y, wres[4 * cq + 1], acc);
            acc = fmaf(r.z, wres[4 * cq + 2], acc);
            acc = fmaf(r.w, wres[4 * cq + 3], acc);
        }
        xe[(size_t)t * HD + lane] = acc;                     // coalesced
        float t0 = acc * as_, t1 = acc * ad_;
        if (H == 8) {
            #pragma unroll
            for (int m = 1; m < 8; m <<= 1) {
                t0 += __shfl_xor(t0, m, 64);
                t1 += __shfl_xor(t1, m, 64);
            }
            if ((lane & 7) == 0) {
                es[t * 8 + (lane >> 3)] = t0;
                ed[t * 8 + (lane >> 3)] = t1;
            }
        } else {
            #pragma unroll
            for (int m = 1; m < 64; m <<= 1) {
                t0 += __shfl_xor(t0, m, 64);
                t1 += __shfl_xor(t1, m, 64);
            }
            if (lane == 0) { es[t] = t0; ed[t] = t1; }
        }
    }
}

// layer 0: proj fused in. h row computed per-lane, broadcast via LDS row write.
__global__ __launch_bounds__(256, 4)
void fused0_kernel(const float* __restrict__ x, const float* __restrict__ pw,
                   const float* __restrict__ pb, const float* __restrict__ w,
                   const float* __restrict__ asrc, const float* __restrict__ adst,
                   float* __restrict__ xe, float* __restrict__ es, float* __restrict__ ed) {
    __shared__ float tile[GT * HD];
    __shared__ float xt[S * GT];
    int base = blockIdx.x * GT;
    for (int i = threadIdx.x; i < S * GT; i += 256) {
        int s = i >> 6, nl = i & 63;
        int t = base + nl, bb = t / N, n = t - bb * N;
        xt[i] = x[(bb * S + s) * N + n];          // coalesced per s-segment
    }
    int lane = threadIdx.x & 63;
    float wres[HD];
    #pragma unroll
    for (int c = 0; c < HD; ++c) wres[c] = w[c * HD + lane];
    float pwres[S];
    #pragma unroll
    for (int s = 0; s < S; ++s) pwres[s] = pw[s * HD + lane];
    float pbv = pb[lane];
    float as_ = asrc[lane], ad_ = adst[lane];
    __syncthreads();
    int wvid = threadIdx.x >> 6;
    // phase A: this wave's 16 h-rows (lane = channel), written to tile
    for (int j = wvid * 16; j < wvid * 16 + 16; ++j) {
        float hl = pbv;
        #pragma unroll
        for (int s = 0; s < S; ++s)
            hl = fmaf(xt[s * GT + j], pwres[s], hl);         // broadcast read
        tile[j * HD + lane] = hl;                            // own wave's row
    }
    // phase B: gemm + attn (reads only this wave's rows -> no barrier needed)
    for (int j = wvid * 16; j < wvid * 16 + 16; ++j) {
        int t = base + j;
        float acc = 0.f;
        #pragma unroll
        for (int cq = 0; cq < 16; ++cq) {
            float4 r = ((const float4*)tile)[j * 16 + cq];
            acc = fmaf(r.x, wres[4 * cq + 0], acc);
            acc = fmaf(r.y, wres[4 * cq + 1], acc);
            acc = fmaf(r.z, wres[4 * cq + 2], acc);
            acc = fmaf(r.w, wres[4 * cq + 3], acc);
        }
        xe[(size_t)t * HD + lane] = acc;
        float t0 = acc * as_, t1 = acc * ad_;
        #pragma unroll
        for (int m = 1; m < 8; m <<= 1) {
            t0 += __shfl_xor(t0, m, 64);
            t1 += __shfl_xor(t1, m, 64);
        }
        if ((lane & 7) == 0) {
            es[t * 8 + (lane >> 3)] = t0;
            ed[t * 8 + (lane >> 3)] = t1;
        }
    }
}

// ------- fused aggregation (R13 proven form): one wave per (batch,node) ------
// 4 groups x 16 lanes; group owns an edge, lane owns 4 channels (float4).
template<int H, bool DO_ELU>
__global__ __launch_bounds__(256, 8)
void agg_kernel(const float* __restrict__ xe, const float* __restrict__ es,
                const float* __restrict__ ed, const int* __restrict__ cnt,
                const int* __restrict__ perm, const float* __restrict__ bias,
                float* __restrict__ hout) {
    int g = blockIdx.x;                       // 20000 blocks, multiple of 8
    int bb   = (g & 7) >> 1;                  // batch from XCD pair
    int idx  = (g >> 3) * 2 + (g & 1);        // 0..4999 within batch
    int node = idx * 4 + (threadIdx.x >> 6);  // < 20000
    int lane  = threadIdx.x & 63;
    int group = lane >> 4;
    int c4    = lane & 15;
    int deg = cnt[node];
    int baseE = node * CAP;
    int h = (H == 8) ? (c4 >> 1) : 0;        // channels 4*c4..+3 lie in one head
    const float*  es_b = es + bb * (N * H);
    const float4* xe4  = (const float4*)(xe + bb * (N * HD));
    float edv = ed[(bb * N + node) * H + h];
    float4 acc = {0.f, 0.f, 0.f, 0.f};
    float ssum = 0.f;
    #pragma unroll 4
    for (int jb = 0; jb < deg; jb += 4) {
        int j = jb + group;
        bool valid = (j < deg);
        int src = perm[baseE + (valid ? j : 0)];     // slot 0 always exists
        float e = es_b[src * H + h] + edv;
        e = fmaxf(e, 0.2f * e);                      // leaky_relu(0.2)
        float p = valid ? __expf(e) : 0.f;
        ssum += p;
        float4 xv = xe4[src * 16 + c4];              // 256B/group gather
        acc.x = fmaf(p, xv.x, acc.x);
        acc.y = fmaf(p, xv.y, acc.y);
        acc.z = fmaf(p, xv.z, acc.z);
        acc.w = fmaf(p, xv.w, acc.w);
    }
    #pragma unroll
    for (int m = 16; m < 64; m <<= 1) {
        acc.x += __shfl_xor(acc.x, m, 64);
        acc.y += __shfl_xor(acc.y, m, 64);
        acc.z += __shfl_xor(acc.z, m, 64);
        acc.w += __shfl_xor(acc.w, m, 64);
        ssum  += __shfl_xor(ssum,  m, 64);
    }
    if (lane < 16) {
        float inv = 1.f / ssum;
        const float4* b4 = (const float4*)bias;
        float4 bv = b4[c4];
        float4 r;
        r.x = acc.x * inv + bv.x;
        r.y = acc.y * inv + bv.y;
        r.z = acc.z * inv + bv.z;
        r.w = acc.w * inv + bv.w;
        if (DO_ELU) {
            r.x = (r.x > 0.f) ? r.x : expm1f(r.x);
            r.y = (r.y > 0.f) ? r.y : expm1f(r.y);
            r.z = (r.z > 0.f) ? r.z : expm1f(r.z);
            r.w = (r.w > 0.f) ? r.w : expm1f(r.w);
        }
        ((float4*)hout)[(bb * N + node) * 16 + c4] = r;
    }
}

// ======== conv v10: row-reuse LDS broadcast + LDS-transpose epilogue ========
// Post-mortems: v9 (s_load rows, 133us) — SGPR file (48) can't hold row data,
// scalar pipe serializes. v8 (LDS broadcast, 84us) — WRITE_SIZE 16.5MB showed
// SPILL (compiler chose 64 VGPR / 8 waves-EU), plus 3.84M ds_reads (each row
// read 3x, once per dt). v10 keeps the proven gemm_attn LDS-broadcast data
// path and fixes both:
//   - row-reuse: read each tile row ONCE, scatter into acc[rr],acc[rr-1],
//     acc[rr-2] with all 3 dt weight sets resident (96 VGPR). ds_read per
//     wave 384 -> 192; ds:FMA 1:4 -> 1:12. Total issues 3.84M -> 1.54M.
//   - __launch_bounds__(256,3): VGPR cap ~168, live ~150 -> NO spill.
//   - epilogue: butterfly (180 swizzle/wave) replaced by LDS transpose:
//     write relu(acc) to pad-68 rows (2-way write, ~5-way read), 3 waves do
//     the 64->3 projection with wave-uniform ow (s_load) + coalesced store.
constexpr int CVN3 = 40;                // nodes per (4-wave) block; 20000/40=500
__global__ __launch_bounds__(256, 3)
void conv_out_kernel(const float* __restrict__ h, const float* __restrict__ cwD,
                     const float* __restrict__ cb, const float* __restrict__ ow,
                     const float* __restrict__ ob, float* __restrict__ out) {
    // phase 1 layout: [CVN3+2][64] staged rows (2688 floats)
    // phase 2 layout: [CVN3][68] relu'd transpose buffer (2720 floats)
    __shared__ alignas(16) float tile[CVN3 * 68];        // 10.88 KB
    int bb = blockIdx.y;
    int base = blockIdx.x * CVN3;
    const float4* hb4 = (const float4*)(h + (size_t)bb * N * HD);
    for (int i = threadIdx.x; i < (CVN3 + 2) * (HD / 4); i += 256) {
        int r = i >> 4;                 // tile row 0..41 -> node base+r-1
        int m = base + r - 1;
        float4 v = make_float4(0.f, 0.f, 0.f, 0.f);
        if (m >= 0 && m < N) v = hb4[(size_t)m * 16 + (i & 15)];   // coalesced
        ((float4*)tile)[i] = v;         // zero-pad conv boundary
    }
    int lane = threadIdx.x & 63;        // = channel (main) / node (epilogue)
    int wvid = threadIdx.x >> 6;        // 0..3, owns nodes base+wvid*10..+9
    float acc[10];
    {
        float cbv = cb[lane];
        #pragma unroll
        for (int j = 0; j < 10; ++j) acc[j] = cbv;
    }
    __syncthreads();
    #pragma unroll 1
    for (int ch = 0; ch < 2; ++ch) {             // c-halves
        float w0[32], w1[32], w2[32];            // all 3 dt resident: 96 VGPR
        #pragma unroll
        for (int c = 0; c < 32; ++c) {
            w0[c] = cwD[0 * (HD * HD) + (ch * 32 + c) * HD + lane];
            w1[c] = cwD[1 * (HD * HD) + (ch * 32 + c) * HD + lane];
            w2[c] = cwD[2 * (HD * HD) + (ch * 32 + c) * HD + lane];
        }
        #pragma unroll
        for (int rr = 0; rr < 12; ++rr) {        // rows this wave touches
            // tile row (wvid*10+rr) holds node base+wvid*10+rr-1.
            // out jj needs rows jj..jj+2 with weight dt = rr-jj.
            const float4* row =
                (const float4*)(tile + (wvid * 10 + rr) * HD + ch * 32);
            #pragma unroll
            for (int q = 0; q < 8; ++q) {
                float4 r4 = row[q];              // wave-uniform broadcast read
                if (rr <= 9) {                   // dt=0 -> acc[rr]
                    acc[rr] = fmaf(r4.x, w0[4*q+0], acc[rr]);
                    acc[rr] = fmaf(r4.y, w0[4*q+1], acc[rr]);
                    acc[rr] = fmaf(r4.z, w0[4*q+2], acc[rr]);
                    acc[rr] = fmaf(r4.w, w0[4*q+3], acc[rr]);
                }
                if (rr >= 1 && rr <= 10) {       // dt=1 -> acc[rr-1]
                    acc[rr-1] = fmaf(r4.x, w1[4*q+0], acc[rr-1]);
                    acc[rr-1] = fmaf(r4.y, w1[4*q+1], acc[rr-1]);
                    acc[rr-1] = fmaf(r4.z, w1[4*q+2], acc[rr-1]);
                    acc[rr-1] = fmaf(r4.w, w1[4*q+3], acc[rr-1]);
                }
                if (rr >= 2) {                   // dt=2 -> acc[rr-2]
                    acc[rr-2] = fmaf(r4.x, w2[4*q+0], acc[rr-2]);
                    acc[rr-2] = fmaf(r4.y, w2[4*q+1], acc[rr-2]);
                    acc[rr-2] = fmaf(r4.z, w2[4*q+2], acc[rr-2]);
                    acc[rr-2] = fmaf(r4.w, w2[4*q+3], acc[rr-2]);
                }
            }
        }
    }
    // ---- epilogue: relu -> LDS transpose (pad 68) -> 64->3 projection ------
    __syncthreads();                    // halo rows shared: all reads done
    #pragma unroll
    for (int j = 0; j < 10; ++j) {
        int nl = wvid * 10 + j;
        tile[nl * 68 + lane] = fmaxf(acc[j], 0.f);   // banks 2-way: free
    }
    __syncthreads();
    if (wvid < 3 && lane < CVN3) {      // wave = output o, lane = node
        int o = wvid;
        float a = ob[o];
        const float4* prow = (const float4*)(tile + lane * 68);  // 272B: 16-aligned
        #pragma unroll
        for (int q = 0; q < 16; ++q) {
            float4 r4 = prow[q];        // ~5-way bank alias (pad 68)
            a = fmaf(r4.x, ow[(4*q+0) * 3 + o], a);  // ow: wave-uniform s_load
            a = fmaf(r4.y, ow[(4*q+1) * 3 + o], a);
            a = fmaf(r4.z, ow[(4*q+2) * 3 + o], a);
            a = fmaf(r4.w, ow[(4*q+3) * 3 + o], a);
        }
        out[(size_t)bb * 3 * N + o * N + base + lane] = a;       // coalesced
    }
}

extern "C" void kernel_launch(void* const* d_in, const int* in_sizes, int n_in,
                              void* d_out, int out_size, void* d_ws, size_t ws_size,
                              hipStream_t stream) {
    const float* x      = (const float*)d_in[0];
    const int*   ei     = (const int*)  d_in[1];
    const float* proj_w = (const float*)d_in[2];
    const float* proj_b = (const float*)d_in[3];
    const float* g_w [3] = {(const float*)d_in[4], (const float*)d_in[8],  (const float*)d_in[12]};
    const float* g_as[3] = {(const float*)d_in[5], (const float*)d_in[9],  (const float*)d_in[13]};
    const float* g_ad[3] = {(const float*)d_in[6], (const float*)d_in[10], (const float*)d_in[14]};
    const float* g_b [3] = {(const float*)d_in[7], (const float*)d_in[11], (const float*)d_in[15]};
    const float* conv_w = (const float*)d_in[16];
    const float* conv_b = (const float*)d_in[17];
    const float* out_w  = (const float*)d_in[18];
    const float* out_b  = (const float*)d_in[19];
    float* out = (float*)d_out;

    // workspace layout (fp32 elements)
    float* bufA = (float*)d_ws;                      // BN*HD
    float* bufX = bufA + (size_t)BN * HD;            // BN*HD
    float* es   = bufX + (size_t)BN * HD;            // BN*8 (max H)
    float* ed   = es   + (size_t)BN * 8;             // BN*8
    int* cnt  = (int*)(ed + (size_t)BN * 8);         // N
    int* perm = cnt + N;                             // N*CAP
    float* cwD = (float*)(perm + (size_t)N * CAP);   // 3*64*64

    const int TB = 256;
    const int gE = (EL + TB - 1) / TB;

    // CSR build: memset + single scatter (padded buckets, no scan)
    hipMemsetAsync(cnt, 0, N * sizeof(int), stream);
    scatter_kernel<<<gE, TB, 0, stream>>>(ei, cnt, perm);

    // conv weight transpose to [dt][c][o]
    tw_kernel<<<(HD * HD * 3 + TB - 1) / TB, TB, 0, stream>>>(conv_w, cwD);

    // layer 0: proj + gemm + attn fused (reads x directly)
    fused0_kernel<<<BN / GT, TB, 0, stream>>>(x, proj_w, proj_b, g_w[0], g_as[0], g_ad[0],
                                              bufX, es, ed);
    agg_kernel<8, true><<<BN / 4, TB, 0, stream>>>(bufX, es, ed, cnt, perm, g_b[0], bufA);

    // layer 1 (H=8) + ELU
    gemm_attn_kernel<8><<<BN / GT, TB, 0, stream>>>(bufA, g_w[1], g_as[1], g_ad[1], bufX, es, ed);
    agg_kernel<8, true><<<BN / 4, TB, 0, stream>>>(bufX, es, ed, cnt, perm, g_b[1], bufA);

    // layer 2 (H=1), no ELU
    gemm_attn_kernel<1><<<BN / GT, TB, 0, stream>>>(bufA, g_w[2], g_as[2], g_ad[2], bufX, es, ed);
    agg_kernel<1, false><<<BN / 4, TB, 0, stream>>>(bufX, es, ed, cnt, perm, g_b[2], bufA);

    // conv1d(k=3) + relu + final projection, writes [B,3,N]
    conv_out_kernel<<<dim3(N / CVN3, B), TB, 0, stream>>>(bufA, cwD, conv_b, out_w, out_b, out);
}

// Round 6
// 650.012 us; speedup vs baseline: 1.6324x; 1.6324x over previous
//
#include <hip/hip_runtime.h>
#include <math.h>

constexpr int B  = 4;
constexpr int S  = 12;
constexpr int N  = 20000;
constexpr int HD = 64;
constexpr int E0 = 640000;
constexpr int EL = E0 + N;      // edges + self loops
constexpr int BN = B * N;
constexpr int CAP = 128;        // padded CSR bucket capacity (deg: mean 32, sd 5.7)

// ---------------- padded-bucket CSR build: one kernel, no scan ---------------
__global__ void scatter_kernel(const int* __restrict__ ei, int* __restrict__ cnt,
                               int* __restrict__ perm) {
    int e = blockIdx.x * blockDim.x + threadIdx.x;
    if (e >= EL) return;
    int s, d;
    if (e < E0) { s = ei[e]; d = ei[E0 + e]; }
    else        { s = e - E0; d = s; }
    int pos = atomicAdd(&cnt[d], 1) & (CAP - 1);   // mask: can't corrupt neighbors
    perm[d * CAP + pos] = s;
}

// ---- conv weight transpose: cwD[dt*4096 + c*64 + o] = cw[o*192 + c*3 + dt] --
__global__ void tw_kernel(const float* __restrict__ cw, float* __restrict__ cwD) {
    int i = blockIdx.x * blockDim.x + threadIdx.x;
    if (i >= HD * HD * 3) return;
    int o = i / (HD * 3), rem = i % (HD * 3), c = rem / 3, dt = rem % 3;
    cwD[dt * (HD * HD) + c * HD + o] = cw[i];
}

// ======== gemm family v3 (R13-proven): lane = k, weights resident in VGPRs ==
// wave processes 16 nodes; node rows broadcast from LDS (wave-uniform addr);
// xe stored directly (coalesced 256B per node); es/ed via butterfly shuffle.
// (v4 1-wave s_load variant measured +9us/dispatch worse — R15.)
constexpr int GT = 64;                  // nodes per block (4 waves x 16)

template<int H>
__global__ __launch_bounds__(256, 4)
void gemm_attn_kernel(const float* __restrict__ hin, const float* __restrict__ w,
                      const float* __restrict__ asrc, const float* __restrict__ adst,
                      float* __restrict__ xe, float* __restrict__ es, float* __restrict__ ed) {
    __shared__ float tile[GT * HD];
    int base = blockIdx.x * GT;
    for (int i = threadIdx.x; i < GT * (HD / 4); i += 256)
        ((float4*)tile)[i] = ((const float4*)(hin + (size_t)base * HD))[i];
    int lane = threadIdx.x & 63;
    float wres[HD];                     // w[c][lane], c compile-time -> VGPRs
    #pragma unroll
    for (int c = 0; c < HD; ++c) wres[c] = w[c * HD + lane];
    float as_ = asrc[lane], ad_ = adst[lane];
    __syncthreads();
    int wvid = threadIdx.x >> 6;
    for (int j = wvid * 16; j < wvid * 16 + 16; ++j) {
        int t = base + j;
        float acc = 0.f;
        #pragma unroll
        for (int cq = 0; cq < 16; ++cq) {
            float4 r = ((const float4*)tile)[j * 16 + cq];   // broadcast read
            acc = fmaf(r.x, wres[4 * cq + 0], acc);
            acc = fmaf(r.y, wres[4 * cq + 1], acc);
            acc = fmaf(r.z, wres[4 * cq + 2], acc);
            acc = fmaf(r.w, wres[4 * cq + 3], acc);
        }
        xe[(size_t)t * HD + lane] = acc;                     // coalesced
        float t0 = acc * as_, t1 = acc * ad_;
        if (H == 8) {
            #pragma unroll
            for (int m = 1; m < 8; m <<= 1) {
                t0 += __shfl_xor(t0, m, 64);
                t1 += __shfl_xor(t1, m, 64);
            }
            if ((lane & 7) == 0) {
                es[t * 8 + (lane >> 3)] = t0;
                ed[t * 8 + (lane >> 3)] = t1;
            }
        } else {
            #pragma unroll
            for (int m = 1; m < 64; m <<= 1) {
                t0 += __shfl_xor(t0, m, 64);
                t1 += __shfl_xor(t1, m, 64);
            }
            if (lane == 0) { es[t] = t0; ed[t] = t1; }
        }
    }
}

// layer 0: proj fused in. h row computed per-lane, broadcast via LDS row write.
__global__ __launch_bounds__(256, 4)
void fused0_kernel(const float* __restrict__ x, const float* __restrict__ pw,
                   const float* __restrict__ pb, const float* __restrict__ w,
                   const float* __restrict__ asrc, const float* __restrict__ adst,
                   float* __restrict__ xe, float* __restrict__ es, float* __restrict__ ed) {
    __shared__ float tile[GT * HD];
    __shared__ float xt[S * GT];
    int base = blockIdx.x * GT;
    for (int i = threadIdx.x; i < S * GT; i += 256) {
        int s = i >> 6, nl = i & 63;
        int t = base + nl, bb = t / N, n = t - bb * N;
        xt[i] = x[(bb * S + s) * N + n];          // coalesced per s-segment
    }
    int lane = threadIdx.x & 63;
    float wres[HD];
    #pragma unroll
    for (int c = 0; c < HD; ++c) wres[c] = w[c * HD + lane];
    float pwres[S];
    #pragma unroll
    for (int s = 0; s < S; ++s) pwres[s] = pw[s * HD + lane];
    float pbv = pb[lane];
    float as_ = asrc[lane], ad_ = adst[lane];
    __syncthreads();
    int wvid = threadIdx.x >> 6;
    // phase A: this wave's 16 h-rows (lane = channel), written to tile
    for (int j = wvid * 16; j < wvid * 16 + 16; ++j) {
        float hl = pbv;
        #pragma unroll
        for (int s = 0; s < S; ++s)
            hl = fmaf(xt[s * GT + j], pwres[s], hl);         // broadcast read
        tile[j * HD + lane] = hl;                            // own wave's row
    }
    // phase B: gemm + attn (reads only this wave's rows -> no barrier needed)
    for (int j = wvid * 16; j < wvid * 16 + 16; ++j) {
        int t = base + j;
        float acc = 0.f;
        #pragma unroll
        for (int cq = 0; cq < 16; ++cq) {
            float4 r = ((const float4*)tile)[j * 16 + cq];
            acc = fmaf(r.x, wres[4 * cq + 0], acc);
            acc = fmaf(r.y, wres[4 * cq + 1], acc);
            acc = fmaf(r.z, wres[4 * cq + 2], acc);
            acc = fmaf(r.w, wres[4 * cq + 3], acc);
        }
        xe[(size_t)t * HD + lane] = acc;
        float t0 = acc * as_, t1 = acc * ad_;
        #pragma unroll
        for (int m = 1; m < 8; m <<= 1) {
            t0 += __shfl_xor(t0, m, 64);
            t1 += __shfl_xor(t1, m, 64);
        }
        if ((lane & 7) == 0) {
            es[t * 8 + (lane >> 3)] = t0;
            ed[t * 8 + (lane >> 3)] = t1;
        }
    }
}

// ------- fused aggregation (R13 proven form): one wave per (batch,node) ------
// 4 groups x 16 lanes; group owns an edge, lane owns 4 channels (float4).
template<int H, bool DO_ELU>
__global__ __launch_bounds__(256, 8)
void agg_kernel(const float* __restrict__ xe, const float* __restrict__ es,
                const float* __restrict__ ed, const int* __restrict__ cnt,
                const int* __restrict__ perm, const float* __restrict__ bias,
                float* __restrict__ hout) {
    int g = blockIdx.x;                       // 20000 blocks, multiple of 8
    int bb   = (g & 7) >> 1;                  // batch from XCD pair
    int idx  = (g >> 3) * 2 + (g & 1);        // 0..4999 within batch
    int node = idx * 4 + (threadIdx.x >> 6);  // < 20000
    int lane  = threadIdx.x & 63;
    int group = lane >> 4;
    int c4    = lane & 15;
    int deg = cnt[node];
    int baseE = node * CAP;
    int h = (H == 8) ? (c4 >> 1) : 0;        // channels 4*c4..+3 lie in one head
    const float*  es_b = es + bb * (N * H);
    const float4* xe4  = (const float4*)(xe + bb * (N * HD));
    float edv = ed[(bb * N + node) * H + h];
    float4 acc = {0.f, 0.f, 0.f, 0.f};
    float ssum = 0.f;
    #pragma unroll 4
    for (int jb = 0; jb < deg; jb += 4) {
        int j = jb + group;
        bool valid = (j < deg);
        int src = perm[baseE + (valid ? j : 0)];     // slot 0 always exists
        float e = es_b[src * H + h] + edv;
        e = fmaxf(e, 0.2f * e);                      // leaky_relu(0.2)
        float p = valid ? __expf(e) : 0.f;
        ssum += p;
        float4 xv = xe4[src * 16 + c4];              // 256B/group gather
        acc.x = fmaf(p, xv.x, acc.x);
        acc.y = fmaf(p, xv.y, acc.y);
        acc.z = fmaf(p, xv.z, acc.z);
        acc.w = fmaf(p, xv.w, acc.w);
    }
    #pragma unroll
    for (int m = 16; m < 64; m <<= 1) {
        acc.x += __shfl_xor(acc.x, m, 64);
        acc.y += __shfl_xor(acc.y, m, 64);
        acc.z += __shfl_xor(acc.z, m, 64);
        acc.w += __shfl_xor(acc.w, m, 64);
        ssum  += __shfl_xor(ssum,  m, 64);
    }
    if (lane < 16) {
        float inv = 1.f / ssum;
        const float4* b4 = (const float4*)bias;
        float4 bv = b4[c4];
        float4 r;
        r.x = acc.x * inv + bv.x;
        r.y = acc.y * inv + bv.y;
        r.z = acc.z * inv + bv.z;
        r.w = acc.w * inv + bv.w;
        if (DO_ELU) {
            r.x = (r.x > 0.f) ? r.x : expm1f(r.x);
            r.y = (r.y > 0.f) ? r.y : expm1f(r.y);
            r.z = (r.z > 0.f) ? r.z : expm1f(r.z);
            r.w = (r.w > 0.f) ? r.w : expm1f(r.w);
        }
        ((float4*)hout)[(bb * N + node) * 16 + c4] = r;
    }
}

// ======== conv v11 = v7.1 EXACT body, 2 waves per workgroup =================
// Post-mortems: v8 84us (spill + 3.84M ds_reads), v9 133us (48 SGPRs can't
// hold row data), v10 700us (acc/w arrays -> scratch; VGPR 84, 2.4GB hbm).
// All three rewrites lost to v7.1's 67us. REVERT to the proven v7.1 inner
// loops (uniform hp[c] -> s_load scalar-pipe row feed, LDS part accumulate,
// butterfly epilogue) and change ONLY the launch shape: v7.1's limiter per
// counters was 1-wave workgroups (Occ 39% at 40 VGPR / 4KB LDS = WG-slot
// cap, not registers/LDS). Two independent v7.1 waves share one 128-thread
// workgroup, each with a private 4KB LDS half — no barrier, no shared state,
// identical per-wave code. WG-slot-implied wave ceiling doubles.
constexpr int CVN = 16;                 // nodes per wave
__global__ __launch_bounds__(128, 8)
void conv_out_kernel(const float* __restrict__ h, const float* __restrict__ cwD,
                     const float* __restrict__ cb, const float* __restrict__ ow,
                     const float* __restrict__ ob, float* __restrict__ out) {
    __shared__ float part[2 * CVN * HD];   // 8KB, wave-private halves
    int bb = blockIdx.y;
    int wvid = threadIdx.x >> 6;           // 0..1
    int base = blockIdx.x * (2 * CVN) + wvid * CVN;   // N = 625*32 exact
    int lane = threadIdx.x & 63;           // = output channel o
    float* wp = part + wvid * (CVN * HD);  // this wave's 4KB slice
    float cbv = cb[lane];
    float ow0 = ow[lane * 3 + 0], ow1 = ow[lane * 3 + 1], ow2 = ow[lane * 3 + 2];
    float ob0 = ob[0], ob1 = ob[1], ob2 = ob[2];
    #pragma unroll
    for (int j = 0; j < CVN; ++j) wp[j * HD + lane] = cbv;
    #pragma unroll 1
    for (int dt = 0; dt < 3; ++dt) {
        float wres[HD];                 // cwD[dt][c][lane], coalesced VMEM
        #pragma unroll
        for (int c = 0; c < HD; ++c) wres[c] = cwD[dt * (HD * HD) + c * HD + lane];
        #pragma unroll 2
        for (int j = 0; j < CVN; ++j) {
            int m = base + j + dt - 1;
            if (m >= 0 && m < N) {      // uniform branch (s_cbranch)
                const float* hp = h + ((size_t)bb * N + m) * HD;   // uniform -> s_load
                float a = 0.f;
                #pragma unroll
                for (int c = 0; c < HD; ++c)
                    a = fmaf(hp[c], wres[c], a);    // v_fma with SGPR operand
                wp[j * HD + lane] += a;             // wave-local LDS RMW
            }
        }
    }
    // epilogue: relu + 64->3 via butterfly
    #pragma unroll 1
    for (int j = 0; j < CVN; ++j) {
        float v = fmaxf(wp[j * HD + lane], 0.f);
        float t0 = v * ow0, t1 = v * ow1, t2 = v * ow2;
        #pragma unroll
        for (int m = 1; m < 64; m <<= 1) {
            t0 += __shfl_xor(t0, m, 64);
            t1 += __shfl_xor(t1, m, 64);
            t2 += __shfl_xor(t2, m, 64);
        }
        int n = base + j;               // always < N (625*32 = 20000)
        if (lane < 3) {
            float r = (lane == 0) ? t0 + ob0 : (lane == 1) ? t1 + ob1 : t2 + ob2;
            out[(size_t)bb * 3 * N + lane * N + n] = r;
        }
    }
}

extern "C" void kernel_launch(void* const* d_in, const int* in_sizes, int n_in,
                              void* d_out, int out_size, void* d_ws, size_t ws_size,
                              hipStream_t stream) {
    const float* x      = (const float*)d_in[0];
    const int*   ei     = (const int*)  d_in[1];
    const float* proj_w = (const float*)d_in[2];
    const float* proj_b = (const float*)d_in[3];
    const float* g_w [3] = {(const float*)d_in[4], (const float*)d_in[8],  (const float*)d_in[12]};
    const float* g_as[3] = {(const float*)d_in[5], (const float*)d_in[9],  (const float*)d_in[13]};
    const float* g_ad[3] = {(const float*)d_in[6], (const float*)d_in[10], (const float*)d_in[14]};
    const float* g_b [3] = {(const float*)d_in[7], (const float*)d_in[11], (const float*)d_in[15]};
    const float* conv_w = (const float*)d_in[16];
    const float* conv_b = (const float*)d_in[17];
    const float* out_w  = (const float*)d_in[18];
    const float* out_b  = (const float*)d_in[19];
    float* out = (float*)d_out;

    // workspace layout (fp32 elements)
    float* bufA = (float*)d_ws;                      // BN*HD
    float* bufX = bufA + (size_t)BN * HD;            // BN*HD
    float* es   = bufX + (size_t)BN * HD;            // BN*8 (max H)
    float* ed   = es   + (size_t)BN * 8;             // BN*8
    int* cnt  = (int*)(ed + (size_t)BN * 8);         // N
    int* perm = cnt + N;                             // N*CAP
    float* cwD = (float*)(perm + (size_t)N * CAP);   // 3*64*64

    const int TB = 256;
    const int gE = (EL + TB - 1) / TB;

    // CSR build: memset + single scatter (padded buckets, no scan)
    hipMemsetAsync(cnt, 0, N * sizeof(int), stream);
    scatter_kernel<<<gE, TB, 0, stream>>>(ei, cnt, perm);

    // conv weight transpose to [dt][c][o]
    tw_kernel<<<(HD * HD * 3 + TB - 1) / TB, TB, 0, stream>>>(conv_w, cwD);

    // layer 0: proj + gemm + attn fused (reads x directly)
    fused0_kernel<<<BN / GT, TB, 0, stream>>>(x, proj_w, proj_b, g_w[0], g_as[0], g_ad[0],
                                              bufX, es, ed);
    agg_kernel<8, true><<<BN / 4, TB, 0, stream>>>(bufX, es, ed, cnt, perm, g_b[0], bufA);

    // layer 1 (H=8) + ELU
    gemm_attn_kernel<8><<<BN / GT, TB, 0, stream>>>(bufA, g_w[1], g_as[1], g_ad[1], bufX, es, ed);
    agg_kernel<8, true><<<BN / 4, TB, 0, stream>>>(bufX, es, ed, cnt, perm, g_b[1], bufA);

    // layer 2 (H=1), no ELU
    gemm_attn_kernel<1><<<BN / GT, TB, 0, stream>>>(bufA, g_w[2], g_as[2], g_ad[2], bufX, es, ed);
    agg_kernel<1, false><<<BN / 4, TB, 0, stream>>>(bufX, es, ed, cnt, perm, g_b[2], bufA);

    // conv1d(k=3) + relu + final projection, writes [B,3,N]
    conv_out_kernel<<<dim3(N / (2 * CVN), B), 128, 0, stream>>>(bufA, cwD, conv_b, out_w, out_b, out);
}

// Round 7
// 450.268 us; speedup vs baseline: 2.3565x; 1.4436x over previous
//
#include <hip/hip_runtime.h>
#include <math.h>

constexpr int B  = 4;
constexpr int S  = 12;
constexpr int N  = 20000;
constexpr int HD = 64;
constexpr int E0 = 640000;
constexpr int EL = E0 + N;      // edges + self loops
constexpr int BN = B * N;
constexpr int CAP = 128;        // padded CSR bucket capacity (deg: mean 32, sd 5.7)

// ---------------- padded-bucket CSR build: one kernel, no scan ---------------
__global__ void scatter_kernel(const int* __restrict__ ei, int* __restrict__ cnt,
                               int* __restrict__ perm) {
    int e = blockIdx.x * blockDim.x + threadIdx.x;
    if (e >= EL) return;
    int s, d;
    if (e < E0) { s = ei[e]; d = ei[E0 + e]; }
    else        { s = e - E0; d = s; }
    int pos = atomicAdd(&cnt[d], 1) & (CAP - 1);   // mask: can't corrupt neighbors
    perm[d * CAP + pos] = s;
}

// ---- conv weight transpose: cwD[dt*4096 + c*64 + o] = cw[o*192 + c*3 + dt] --
__global__ void tw_kernel(const float* __restrict__ cw, float* __restrict__ cwD) {
    int i = blockIdx.x * blockDim.x + threadIdx.x;
    if (i >= HD * HD * 3) return;
    int o = i / (HD * 3), rem = i % (HD * 3), c = rem / 3, dt = rem % 3;
    cwD[dt * (HD * HD) + c * HD + o] = cw[i];
}

// ======== gemm family v3 (R13-proven): lane = k, weights resident in VGPRs ==
// wave processes 16 nodes; node rows broadcast from LDS (wave-uniform addr);
// xe stored directly (coalesced 256B per node); es/ed via butterfly shuffle.
// (v4 1-wave s_load variant measured +9us/dispatch worse — R15.)
constexpr int GT = 64;                  // nodes per block (4 waves x 16)

template<int H>
__global__ __launch_bounds__(256, 4)
void gemm_attn_kernel(const float* __restrict__ hin, const float* __restrict__ w,
                      const float* __restrict__ asrc, const float* __restrict__ adst,
                      float* __restrict__ xe, float* __restrict__ es, float* __restrict__ ed) {
    __shared__ float tile[GT * HD];
    int base = blockIdx.x * GT;
    for (int i = threadIdx.x; i < GT * (HD / 4); i += 256)
        ((float4*)tile)[i] = ((const float4*)(hin + (size_t)base * HD))[i];
    int lane = threadIdx.x & 63;
    float wres[HD];                     // w[c][lane], c compile-time -> VGPRs
    #pragma unroll
    for (int c = 0; c < HD; ++c) wres[c] = w[c * HD + lane];
    float as_ = asrc[lane], ad_ = adst[lane];
    __syncthreads();
    int wvid = threadIdx.x >> 6;
    for (int j = wvid * 16; j < wvid * 16 + 16; ++j) {
        int t = base + j;
        float acc = 0.f;
        #pragma unroll
        for (int cq = 0; cq < 16; ++cq) {
            float4 r = ((const float4*)tile)[j * 16 + cq];   // broadcast read
            acc = fmaf(r.x, wres[4 * cq + 0], acc);
            acc = fmaf(r.y, wres[4 * cq + 1], acc);
            acc = fmaf(r.z, wres[4 * cq + 2], acc);
            acc = fmaf(r.w, wres[4 * cq + 3], acc);
        }
        xe[(size_t)t * HD + lane] = acc;                     // coalesced
        float t0 = acc * as_, t1 = acc * ad_;
        if (H == 8) {
            #pragma unroll
            for (int m = 1; m < 8; m <<= 1) {
                t0 += __shfl_xor(t0, m, 64);
                t1 += __shfl_xor(t1, m, 64);
            }
            if ((lane & 7) == 0) {
                es[t * 8 + (lane >> 3)] = t0;
                ed[t * 8 + (lane >> 3)] = t1;
            }
        } else {
            #pragma unroll
            for (int m = 1; m < 64; m <<= 1) {
                t0 += __shfl_xor(t0, m, 64);
                t1 += __shfl_xor(t1, m, 64);
            }
            if (lane == 0) { es[t] = t0; ed[t] = t1; }
        }
    }
}

// layer 0: proj fused in. h row computed per-lane, broadcast via LDS row write.
__global__ __launch_bounds__(256, 4)
void fused0_kernel(const float* __restrict__ x, const float* __restrict__ pw,
                   const float* __restrict__ pb, const float* __restrict__ w,
                   const float* __restrict__ asrc, const float* __restrict__ adst,
                   float* __restrict__ xe, float* __restrict__ es, float* __restrict__ ed) {
    __shared__ float tile[GT * HD];
    __shared__ float xt[S * GT];
    int base = blockIdx.x * GT;
    for (int i = threadIdx.x; i < S * GT; i += 256) {
        int s = i >> 6, nl = i & 63;
        int t = base + nl, bb = t / N, n = t - bb * N;
        xt[i] = x[(bb * S + s) * N + n];          // coalesced per s-segment
    }
    int lane = threadIdx.x & 63;
    float wres[HD];
    #pragma unroll
    for (int c = 0; c < HD; ++c) wres[c] = w[c * HD + lane];
    float pwres[S];
    #pragma unroll
    for (int s = 0; s < S; ++s) pwres[s] = pw[s * HD + lane];
    float pbv = pb[lane];
    float as_ = asrc[lane], ad_ = adst[lane];
    __syncthreads();
    int wvid = threadIdx.x >> 6;
    // phase A: this wave's 16 h-rows (lane = channel), written to tile
    for (int j = wvid * 16; j < wvid * 16 + 16; ++j) {
        float hl = pbv;
        #pragma unroll
        for (int s = 0; s < S; ++s)
            hl = fmaf(xt[s * GT + j], pwres[s], hl);         // broadcast read
        tile[j * HD + lane] = hl;                            // own wave's row
    }
    // phase B: gemm + attn (reads only this wave's rows -> no barrier needed)
    for (int j = wvid * 16; j < wvid * 16 + 16; ++j) {
        int t = base + j;
        float acc = 0.f;
        #pragma unroll
        for (int cq = 0; cq < 16; ++cq) {
            float4 r = ((const float4*)tile)[j * 16 + cq];
            acc = fmaf(r.x, wres[4 * cq + 0], acc);
            acc = fmaf(r.y, wres[4 * cq + 1], acc);
            acc = fmaf(r.z, wres[4 * cq + 2], acc);
            acc = fmaf(r.w, wres[4 * cq + 3], acc);
        }
        xe[(size_t)t * HD + lane] = acc;
        float t0 = acc * as_, t1 = acc * ad_;
        #pragma unroll
        for (int m = 1; m < 8; m <<= 1) {
            t0 += __shfl_xor(t0, m, 64);
            t1 += __shfl_xor(t1, m, 64);
        }
        if ((lane & 7) == 0) {
            es[t * 8 + (lane >> 3)] = t0;
            ed[t * 8 + (lane >> 3)] = t1;
        }
    }
}

// ------- fused aggregation (R13 proven form): one wave per (batch,node) ------
// 4 groups x 16 lanes; group owns an edge, lane owns 4 channels (float4).
template<int H, bool DO_ELU>
__global__ __launch_bounds__(256, 8)
void agg_kernel(const float* __restrict__ xe, const float* __restrict__ es,
                const float* __restrict__ ed, const int* __restrict__ cnt,
                const int* __restrict__ perm, const float* __restrict__ bias,
                float* __restrict__ hout) {
    int g = blockIdx.x;                       // 20000 blocks, multiple of 8
    int bb   = (g & 7) >> 1;                  // batch from XCD pair
    int idx  = (g >> 3) * 2 + (g & 1);        // 0..4999 within batch
    int node = idx * 4 + (threadIdx.x >> 6);  // < 20000
    int lane  = threadIdx.x & 63;
    int group = lane >> 4;
    int c4    = lane & 15;
    int deg = cnt[node];
    int baseE = node * CAP;
    int h = (H == 8) ? (c4 >> 1) : 0;        // channels 4*c4..+3 lie in one head
    const float*  es_b = es + bb * (N * H);
    const float4* xe4  = (const float4*)(xe + bb * (N * HD));
    float edv = ed[(bb * N + node) * H + h];
    float4 acc = {0.f, 0.f, 0.f, 0.f};
    float ssum = 0.f;
    #pragma unroll 4
    for (int jb = 0; jb < deg; jb += 4) {
        int j = jb + group;
        bool valid = (j < deg);
        int src = perm[baseE + (valid ? j : 0)];     // slot 0 always exists
        float e = es_b[src * H + h] + edv;
        e = fmaxf(e, 0.2f * e);                      // leaky_relu(0.2)
        float p = valid ? __expf(e) : 0.f;
        ssum += p;
        float4 xv = xe4[src * 16 + c4];              // 256B/group gather
        acc.x = fmaf(p, xv.x, acc.x);
        acc.y = fmaf(p, xv.y, acc.y);
        acc.z = fmaf(p, xv.z, acc.z);
        acc.w = fmaf(p, xv.w, acc.w);
    }
    #pragma unroll
    for (int m = 16; m < 64; m <<= 1) {
        acc.x += __shfl_xor(acc.x, m, 64);
        acc.y += __shfl_xor(acc.y, m, 64);
        acc.z += __shfl_xor(acc.z, m, 64);
        acc.w += __shfl_xor(acc.w, m, 64);
        ssum  += __shfl_xor(ssum,  m, 64);
    }
    if (lane < 16) {
        float inv = 1.f / ssum;
        const float4* b4 = (const float4*)bias;
        float4 bv = b4[c4];
        float4 r;
        r.x = acc.x * inv + bv.x;
        r.y = acc.y * inv + bv.y;
        r.z = acc.z * inv + bv.z;
        r.w = acc.w * inv + bv.w;
        if (DO_ELU) {
            r.x = (r.x > 0.f) ? r.x : expm1f(r.x);
            r.y = (r.y > 0.f) ? r.y : expm1f(r.y);
            r.z = (r.z > 0.f) ? r.z : expm1f(r.z);
            r.w = (r.w > 0.f) ? r.w : expm1f(r.w);
        }
        ((float4*)hout)[(bb * N + node) * 16 + c4] = r;
    }
}

// ======== conv v12 = v7.1 EXACT structure + 4-way accumulator ILP ===========
// Scorecard: v7.1 67us; rewrites v8 84 (spill+ds_read flood), v9 133 (SGPR
// starve), v10 700 (scratch), v11 270 (launch_bounds(,8) -> VGPR 32, spill).
// Lesson: launch_bounds is a register-allocator directive; v7.1's codegen
// (VGPR 40, SGPR 96, no spill) only exists at (64,2). REVERT everything.
// Single local change: v7.1's limiter was the 64-deep dependent FMA chain
// (VALUBusy 43%, ~3 waves/SIMD can't fill issue slots at 4-cyc dep latency).
// Split into 4 partial accumulators over c-quarters -> 4x ILP, +3 VGPRs,
// identical memory pattern, identical launch shape.
constexpr int CVN = 16;                 // nodes per (1-wave) block
__global__ __launch_bounds__(64, 2)
void conv_out_kernel(const float* __restrict__ h, const float* __restrict__ cwD,
                     const float* __restrict__ cb, const float* __restrict__ ow,
                     const float* __restrict__ ob, float* __restrict__ out) {
    __shared__ float part[CVN * HD];    // 4KB, wave-private
    int bb = blockIdx.y;
    int base = blockIdx.x * CVN;        // N = 1250*16 exact
    int lane = threadIdx.x;             // = output channel o
    float cbv = cb[lane];
    float ow0 = ow[lane * 3 + 0], ow1 = ow[lane * 3 + 1], ow2 = ow[lane * 3 + 2];
    float ob0 = ob[0], ob1 = ob[1], ob2 = ob[2];
    #pragma unroll
    for (int j = 0; j < CVN; ++j) part[j * HD + lane] = cbv;
    #pragma unroll 1
    for (int dt = 0; dt < 3; ++dt) {
        float wres[HD];                 // cwD[dt][c][lane], coalesced VMEM
        #pragma unroll
        for (int c = 0; c < HD; ++c) wres[c] = cwD[dt * (HD * HD) + c * HD + lane];
        #pragma unroll 2
        for (int j = 0; j < CVN; ++j) {
            int m = base + j + dt - 1;
            if (m >= 0 && m < N) {      // uniform branch (s_cbranch)
                const float* hp = h + ((size_t)bb * N + m) * HD;   // uniform -> s_load
                float a0 = 0.f, a1 = 0.f, a2 = 0.f, a3 = 0.f;      // 4x ILP
                #pragma unroll
                for (int c = 0; c < 16; ++c) {
                    a0 = fmaf(hp[c +  0], wres[c +  0], a0);
                    a1 = fmaf(hp[c + 16], wres[c + 16], a1);
                    a2 = fmaf(hp[c + 32], wres[c + 32], a2);
                    a3 = fmaf(hp[c + 48], wres[c + 48], a3);
                }
                part[j * HD + lane] += (a0 + a1) + (a2 + a3);      // wave-local LDS RMW
            }
        }
    }
    // epilogue: relu + 64->3 via butterfly
    #pragma unroll 1
    for (int j = 0; j < CVN; ++j) {
        float v = fmaxf(part[j * HD + lane], 0.f);
        float t0 = v * ow0, t1 = v * ow1, t2 = v * ow2;
        #pragma unroll
        for (int m = 1; m < 64; m <<= 1) {
            t0 += __shfl_xor(t0, m, 64);
            t1 += __shfl_xor(t1, m, 64);
            t2 += __shfl_xor(t2, m, 64);
        }
        int n = base + j;               // always < N (1250*16 = 20000)
        if (lane < 3) {
            float r = (lane == 0) ? t0 + ob0 : (lane == 1) ? t1 + ob1 : t2 + ob2;
            out[(size_t)bb * 3 * N + lane * N + n] = r;
        }
    }
}

extern "C" void kernel_launch(void* const* d_in, const int* in_sizes, int n_in,
                              void* d_out, int out_size, void* d_ws, size_t ws_size,
                              hipStream_t stream) {
    const float* x      = (const float*)d_in[0];
    const int*   ei     = (const int*)  d_in[1];
    const float* proj_w = (const float*)d_in[2];
    const float* proj_b = (const float*)d_in[3];
    const float* g_w [3] = {(const float*)d_in[4], (const float*)d_in[8],  (const float*)d_in[12]};
    const float* g_as[3] = {(const float*)d_in[5], (const float*)d_in[9],  (const float*)d_in[13]};
    const float* g_ad[3] = {(const float*)d_in[6], (const float*)d_in[10], (const float*)d_in[14]};
    const float* g_b [3] = {(const float*)d_in[7], (const float*)d_in[11], (const float*)d_in[15]};
    const float* conv_w = (const float*)d_in[16];
    const float* conv_b = (const float*)d_in[17];
    const float* out_w  = (const float*)d_in[18];
    const float* out_b  = (const float*)d_in[19];
    float* out = (float*)d_out;

    // workspace layout (fp32 elements)
    float* bufA = (float*)d_ws;                      // BN*HD
    float* bufX = bufA + (size_t)BN * HD;            // BN*HD
    float* es   = bufX + (size_t)BN * HD;            // BN*8 (max H)
    float* ed   = es   + (size_t)BN * 8;             // BN*8
    int* cnt  = (int*)(ed + (size_t)BN * 8);         // N
    int* perm = cnt + N;                             // N*CAP
    float* cwD = (float*)(perm + (size_t)N * CAP);   // 3*64*64

    const int TB = 256;
    const int gE = (EL + TB - 1) / TB;

    // CSR build: memset + single scatter (padded buckets, no scan)
    hipMemsetAsync(cnt, 0, N * sizeof(int), stream);
    scatter_kernel<<<gE, TB, 0, stream>>>(ei, cnt, perm);

    // conv weight transpose to [dt][c][o]
    tw_kernel<<<(HD * HD * 3 + TB - 1) / TB, TB, 0, stream>>>(conv_w, cwD);

    // layer 0: proj + gemm + attn fused (reads x directly)
    fused0_kernel<<<BN / GT, TB, 0, stream>>>(x, proj_w, proj_b, g_w[0], g_as[0], g_ad[0],
                                              bufX, es, ed);
    agg_kernel<8, true><<<BN / 4, TB, 0, stream>>>(bufX, es, ed, cnt, perm, g_b[0], bufA);

    // layer 1 (H=8) + ELU
    gemm_attn_kernel<8><<<BN / GT, TB, 0, stream>>>(bufA, g_w[1], g_as[1], g_ad[1], bufX, es, ed);
    agg_kernel<8, true><<<BN / 4, TB, 0, stream>>>(bufX, es, ed, cnt, perm, g_b[1], bufA);

    // layer 2 (H=1), no ELU
    gemm_attn_kernel<1><<<BN / GT, TB, 0, stream>>>(bufA, g_w[2], g_as[2], g_ad[2], bufX, es, ed);
    agg_kernel<1, false><<<BN / 4, TB, 0, stream>>>(bufX, es, ed, cnt, perm, g_b[2], bufA);

    // conv1d(k=3) + relu + final projection, writes [B,3,N]
    conv_out_kernel<<<dim3(N / CVN, B), 64, 0, stream>>>(bufA, cwD, conv_b, out_w, out_b, out);
}